// Round 1
// baseline (2837.485 us; speedup 1.0000x reference)
//
#include <hip/hip_runtime.h>
#include <math.h>

namespace {

constexpr int   B_  = 2;
constexpr int   N_  = 16384;
constexpr int   M_  = 2048;
constexpr int   D_  = 256;
constexpr float SCALE_  = 0.0625f;   // 1/sqrt(256)
constexpr float LN_EPS_ = 1e-5f;
constexpr int   NS_  = 8;            // n-splits in attention output kernel
constexpr int   NPB_ = N_ / NS_;     // 2048 n per block

// ---------------- K0: pv MLP -> kpv buffer ----------------
__global__ void pv_prep(const float* __restrict__ p_xyz, const float* __restrict__ v_xyz,
                        const float* __restrict__ Wp1, const float* __restrict__ bp1,
                        const float* __restrict__ ln_w, const float* __restrict__ ln_b,
                        const float* __restrict__ Wp2, const float* __restrict__ bp2,
                        float* __restrict__ kpv) {
    const int r = blockIdx.x;            // flat row in [0, B*N)
    const int b = r / N_;
    const int d = threadIdx.x;           // 0..255
    const float d0 = fabsf(p_xyz[r*3+0] - v_xyz[b*3+0]);
    const float d1 = fabsf(p_xyz[r*3+1] - v_xyz[b*3+1]);
    const float d2 = fabsf(p_xyz[r*3+2] - v_xyz[b*3+2]);
    float h[3];
    #pragma unroll
    for (int j = 0; j < 3; ++j)
        h[j] = d0*Wp1[0*3+j] + d1*Wp1[1*3+j] + d2*Wp1[2*3+j] + bp1[j];
    const float mu = (h[0]+h[1]+h[2]) * (1.0f/3.0f);
    const float e0 = h[0]-mu, e1 = h[1]-mu, e2 = h[2]-mu;
    const float var = (e0*e0 + e1*e1 + e2*e2) * (1.0f/3.0f);
    const float inv = rsqrtf(var + LN_EPS_);
    const float hr0 = fmaxf(e0*inv*ln_w[0] + ln_b[0], 0.0f);
    const float hr1 = fmaxf(e1*inv*ln_w[1] + ln_b[1], 0.0f);
    const float hr2 = fmaxf(e2*inv*ln_w[2] + ln_b[2], 0.0f);
    kpv[r*D_ + d] = hr0*Wp2[0*D_+d] + hr1*Wp2[1*D_+d] + hr2*Wp2[2*D_+d] + bp2[d];
}

// ---------------- K1: C[r][c] (+)= A[r][:] @ W[:][c] + bias[c] ----------------
// 64x64 tile, 256 threads, 4x4 micro-tile, K staged in 64-chunks.
template<bool ACC>
__global__ void gemm_rm(const float* __restrict__ A, const float* __restrict__ W,
                        const float* __restrict__ bias, float* __restrict__ C) {
    __shared__ __align__(16) float As[64*64];   // [k][row]
    __shared__ __align__(16) float Bs[64*64];   // [k][col]
    const int tid = threadIdx.x;
    const int tm = tid >> 4;
    const int tn = tid & 15;
    const int r0 = blockIdx.x * 64;
    const int c0 = blockIdx.y * 64;
    float acc[4][4] = {};
    for (int kt = 0; kt < D_; kt += 64) {
        #pragma unroll
        for (int rr = 0; rr < 4; ++rr) {        // A tile, transpose to [k][row]
            const int idx = tid + rr*256;
            const int row = idx >> 4;
            const int kq  = (idx & 15) << 2;
            const float4 v = *reinterpret_cast<const float4*>(&A[(r0+row)*D_ + kt + kq]);
            As[(kq+0)*64 + row] = v.x;
            As[(kq+1)*64 + row] = v.y;
            As[(kq+2)*64 + row] = v.z;
            As[(kq+3)*64 + row] = v.w;
        }
        #pragma unroll
        for (int rr = 0; rr < 4; ++rr) {        // W tile, already k-major
            const int idx = tid + rr*256;
            const int krow = idx >> 4;
            const int cq   = (idx & 15) << 2;
            *reinterpret_cast<float4*>(&Bs[krow*64 + cq]) =
                *reinterpret_cast<const float4*>(&W[(kt+krow)*D_ + c0 + cq]);
        }
        __syncthreads();
        #pragma unroll 8
        for (int k = 0; k < 64; ++k) {
            const float4 a4 = *reinterpret_cast<const float4*>(&As[k*64 + tm*4]);
            const float4 b4 = *reinterpret_cast<const float4*>(&Bs[k*64 + tn*4]);
            const float a[4] = {a4.x, a4.y, a4.z, a4.w};
            const float b[4] = {b4.x, b4.y, b4.z, b4.w};
            #pragma unroll
            for (int i = 0; i < 4; ++i)
                #pragma unroll
                for (int j = 0; j < 4; ++j)
                    acc[i][j] = fmaf(a[i], b[j], acc[i][j]);
        }
        __syncthreads();
    }
    const float4 bias4 = *reinterpret_cast<const float4*>(&bias[c0 + tn*4]);
    const float bb[4] = {bias4.x, bias4.y, bias4.z, bias4.w};
    #pragma unroll
    for (int i = 0; i < 4; ++i) {
        float* cp = &C[(r0 + tm*4 + i)*D_ + c0 + tn*4];
        float4 o;
        o.x = acc[i][0] + bb[0];
        o.y = acc[i][1] + bb[1];
        o.z = acc[i][2] + bb[2];
        o.w = acc[i][3] + bb[3];
        if (ACC) {
            const float4 old = *reinterpret_cast<const float4*>(cp);
            o.x += old.x; o.y += old.y; o.z += old.z; o.w += old.w;
        }
        *reinterpret_cast<float4*>(cp) = o;
    }
}

// ---------------- K2: per-(b,n) softmax stats over m ----------------
// One block per 64 n-rows; online max/sumexp over m in 64-tiles.
__global__ void col_stats(const float* __restrict__ kpv, const float* __restrict__ q,
                          float* __restrict__ cmax, float* __restrict__ cinv) {
    __shared__ __align__(16) float As[64*64];   // [k][n] kpv
    __shared__ __align__(16) float Bs[64*64];   // [k][m] q
    __shared__ float red[64*17];
    __shared__ float rmax[64];
    __shared__ float rsum[64];
    const int tid = threadIdx.x;
    const int tA = tid >> 4;     // n micro group
    const int tB = tid & 15;     // m micro group
    const int bn0 = blockIdx.x * 64;        // flat n-row base
    const int b = bn0 / N_;
    if (tid < 64) { rmax[tid] = -INFINITY; rsum[tid] = 0.0f; }
    __syncthreads();
    for (int mt = 0; mt < M_; mt += 64) {
        float s[4][4] = {};
        for (int kt = 0; kt < D_; kt += 64) {
            #pragma unroll
            for (int rr = 0; rr < 4; ++rr) {
                const int idx = tid + rr*256;
                const int row = idx >> 4;
                const int kq  = (idx & 15) << 2;
                const float4 v = *reinterpret_cast<const float4*>(&kpv[(bn0+row)*D_ + kt + kq]);
                As[(kq+0)*64 + row] = v.x;
                As[(kq+1)*64 + row] = v.y;
                As[(kq+2)*64 + row] = v.z;
                As[(kq+3)*64 + row] = v.w;
            }
            #pragma unroll
            for (int rr = 0; rr < 4; ++rr) {
                const int idx = tid + rr*256;
                const int row = idx >> 4;
                const int kq  = (idx & 15) << 2;
                const float4 v = *reinterpret_cast<const float4*>(&q[(b*M_ + mt + row)*D_ + kt + kq]);
                Bs[(kq+0)*64 + row] = v.x;
                Bs[(kq+1)*64 + row] = v.y;
                Bs[(kq+2)*64 + row] = v.z;
                Bs[(kq+3)*64 + row] = v.w;
            }
            __syncthreads();
            #pragma unroll 8
            for (int k = 0; k < 64; ++k) {
                const float4 a4 = *reinterpret_cast<const float4*>(&As[k*64 + tA*4]);
                const float4 b4 = *reinterpret_cast<const float4*>(&Bs[k*64 + tB*4]);
                const float a[4] = {a4.x, a4.y, a4.z, a4.w};
                const float b[4] = {b4.x, b4.y, b4.z, b4.w};
                #pragma unroll
                for (int i = 0; i < 4; ++i)
                    #pragma unroll
                    for (int j = 0; j < 4; ++j)
                        s[i][j] = fmaf(a[i], b[j], s[i][j]);
            }
            __syncthreads();
        }
        // ---- tile max per n ----
        #pragma unroll
        for (int ni = 0; ni < 4; ++ni) {
            float mx = fmaxf(fmaxf(s[ni][0], s[ni][1]), fmaxf(s[ni][2], s[ni][3]));
            red[(tA*4+ni)*17 + tB] = mx * SCALE_;
        }
        __syncthreads();
        float factor = 0.0f;
        if (tid < 64) {
            float tmax = red[tid*17 + 0];
            #pragma unroll
            for (int j = 1; j < 16; ++j) tmax = fmaxf(tmax, red[tid*17 + j]);
            const float nm = fmaxf(rmax[tid], tmax);
            factor = __expf(rmax[tid] - nm);   // exp(-inf)=0 on first tile
            rmax[tid] = nm;
        }
        __syncthreads();
        // ---- tile sumexp with new max ----
        #pragma unroll
        for (int ni = 0; ni < 4; ++ni) {
            const float nm = rmax[tA*4 + ni];
            float ps = 0.0f;
            #pragma unroll
            for (int mj = 0; mj < 4; ++mj)
                ps += __expf(s[ni][mj]*SCALE_ - nm);
            red[(tA*4+ni)*17 + tB] = ps;
        }
        __syncthreads();
        if (tid < 64) {
            float ts = 0.0f;
            #pragma unroll
            for (int j = 0; j < 16; ++j) ts += red[tid*17 + j];
            rsum[tid] = rsum[tid]*factor + ts;
        }
        __syncthreads();
    }
    if (tid < 64) {
        cmax[bn0 + tid] = rmax[tid];
        cinv[bn0 + tid] = 1.0f / rsum[tid];
    }
}

// ---------------- K3: out = v_features ----------------
__global__ void init_out(const float* __restrict__ src, float* __restrict__ dst) {
    const int i = blockIdx.x * blockDim.x + threadIdx.x;
    reinterpret_cast<float4*>(dst)[i] = reinterpret_cast<const float4*>(src)[i];
}

// ---------------- K4: out[m][:] += sum_n w[m][n] * v[n][:] ----------------
// grid: b * ns(8 n-splits) * mt(32 m-tiles of 64). Accumulates full 64m x 256d
// tile in registers over its 2048 n's, then one atomicAdd tile.
__global__ void attn_out(const float* __restrict__ q, const float* __restrict__ kpv,
                         const float* __restrict__ vv, const float* __restrict__ cmax,
                         const float* __restrict__ cinv, float* __restrict__ out) {
    __shared__ __align__(16) float As[64*64];     // [k][m] q
    __shared__ __align__(16) float Bs[64*64];     // [k][n] kpv
    __shared__ float wS[64*65];                   // [m][n], +1 pad
    __shared__ __align__(16) float Vs[64*68];     // [n][d-chunk], +4 pad
    __shared__ float cmS[64];
    __shared__ float ciS[64];
    const int tid = threadIdx.x;
    const int tm = tid >> 4;
    const int tn = tid & 15;
    const int bid = blockIdx.x;
    const int mt = bid & 31;
    const int ns = (bid >> 5) & (NS_ - 1);
    const int b  = bid >> 8;
    const int m0 = mt * 64;

    float4 o[4][4];   // [mi][d-chunk]
    #pragma unroll
    for (int i = 0; i < 4; ++i)
        #pragma unroll
        for (int c = 0; c < 4; ++c)
            o[i][c] = make_float4(0.f, 0.f, 0.f, 0.f);

    for (int nt = 0; nt < NPB_; nt += 64) {
        const int gn = ns*NPB_ + nt;            // within-batch n base
        if (tid < 64) {
            cmS[tid] = cmax[b*N_ + gn + tid];
            ciS[tid] = cinv[b*N_ + gn + tid];
        }
        float s[4][4] = {};
        for (int kt = 0; kt < D_; kt += 64) {
            #pragma unroll
            for (int rr = 0; rr < 4; ++rr) {    // q -> As [k][m]
                const int idx = tid + rr*256;
                const int row = idx >> 4;
                const int kq  = (idx & 15) << 2;
                const float4 v = *reinterpret_cast<const float4*>(&q[(b*M_ + m0 + row)*D_ + kt + kq]);
                As[(kq+0)*64 + row] = v.x;
                As[(kq+1)*64 + row] = v.y;
                As[(kq+2)*64 + row] = v.z;
                As[(kq+3)*64 + row] = v.w;
            }
            #pragma unroll
            for (int rr = 0; rr < 4; ++rr) {    // kpv -> Bs [k][n]
                const int idx = tid + rr*256;
                const int row = idx >> 4;
                const int kq  = (idx & 15) << 2;
                const float4 v = *reinterpret_cast<const float4*>(&kpv[(b*N_ + gn + row)*D_ + kt + kq]);
                Bs[(kq+0)*64 + row] = v.x;
                Bs[(kq+1)*64 + row] = v.y;
                Bs[(kq+2)*64 + row] = v.z;
                Bs[(kq+3)*64 + row] = v.w;
            }
            __syncthreads();
            #pragma unroll 8
            for (int k = 0; k < 64; ++k) {
                const float4 a4 = *reinterpret_cast<const float4*>(&As[k*64 + tm*4]);
                const float4 b4 = *reinterpret_cast<const float4*>(&Bs[k*64 + tn*4]);
                const float a[4] = {a4.x, a4.y, a4.z, a4.w};
                const float bv[4] = {b4.x, b4.y, b4.z, b4.w};
                #pragma unroll
                for (int i = 0; i < 4; ++i)
                    #pragma unroll
                    for (int j = 0; j < 4; ++j)
                        s[i][j] = fmaf(a[i], bv[j], s[i][j]);
            }
            __syncthreads();
        }
        // weights -> LDS (covered by the sync after the first Vs staging)
        #pragma unroll
        for (int mi = 0; mi < 4; ++mi)
            #pragma unroll
            for (int nj = 0; nj < 4; ++nj) {
                const int n = tn*4 + nj;
                wS[(tm*4+mi)*65 + n] = __expf(s[mi][nj]*SCALE_ - cmS[n]) * ciS[n];
            }
        #pragma unroll
        for (int ch = 0; ch < 4; ++ch) {
            #pragma unroll
            for (int rr = 0; rr < 4; ++rr) {    // vv chunk -> Vs [n][d]
                const int idx = tid + rr*256;
                const int row = idx >> 4;
                const int dq  = (idx & 15) << 2;
                *reinterpret_cast<float4*>(&Vs[row*68 + dq]) =
                    *reinterpret_cast<const float4*>(&vv[(b*N_ + gn + row)*D_ + ch*64 + dq]);
            }
            __syncthreads();
            #pragma unroll 8
            for (int n = 0; n < 64; ++n) {
                const float4 v4 = *reinterpret_cast<const float4*>(&Vs[n*68 + tn*4]);
                #pragma unroll
                for (int mi = 0; mi < 4; ++mi) {
                    const float w = wS[(tm*4+mi)*65 + n];
                    o[mi][ch].x = fmaf(w, v4.x, o[mi][ch].x);
                    o[mi][ch].y = fmaf(w, v4.y, o[mi][ch].y);
                    o[mi][ch].z = fmaf(w, v4.z, o[mi][ch].z);
                    o[mi][ch].w = fmaf(w, v4.w, o[mi][ch].w);
                }
            }
            __syncthreads();
        }
    }
    #pragma unroll
    for (int mi = 0; mi < 4; ++mi) {
        #pragma unroll
        for (int ch = 0; ch < 4; ++ch) {
            float* p = &out[(b*M_ + m0 + tm*4 + mi)*D_ + ch*64 + tn*4];
            atomicAdd(p+0, o[mi][ch].x);
            atomicAdd(p+1, o[mi][ch].y);
            atomicAdd(p+2, o[mi][ch].z);
            atomicAdd(p+3, o[mi][ch].w);
        }
    }
}

} // anonymous namespace

extern "C" void kernel_launch(void* const* d_in, const int* in_sizes, int n_in,
                              void* d_out, int out_size, void* d_ws, size_t ws_size,
                              hipStream_t stream) {
    const float* p_xyz      = (const float*)d_in[0];
    const float* v_xyz      = (const float*)d_in[1];
    const float* p_features = (const float*)d_in[2];
    const float* v_features = (const float*)d_in[3];
    const float* Wq  = (const float*)d_in[4];
    const float* bq  = (const float*)d_in[5];
    const float* Wk  = (const float*)d_in[6];
    const float* bk  = (const float*)d_in[7];
    const float* Wv  = (const float*)d_in[8];
    const float* bv  = (const float*)d_in[9];
    const float* Wp1 = (const float*)d_in[10];
    const float* bp1 = (const float*)d_in[11];
    const float* lnw = (const float*)d_in[12];
    const float* lnb = (const float*)d_in[13];
    const float* Wp2 = (const float*)d_in[14];
    const float* bp2 = (const float*)d_in[15];
    float* out = (float*)d_out;

    // workspace layout (floats): q | kpv | vv | cmax | cinv   = 71.6 MB total
    float* ws  = (float*)d_ws;
    float* q   = ws;                                   // B*M*D
    float* kpv = q   + (size_t)B_*M_*D_;               // B*N*D
    float* vv  = kpv + (size_t)B_*N_*D_;               // B*N*D
    float* cm  = vv  + (size_t)B_*N_*D_;               // B*N
    float* ci  = cm  + (size_t)B_*N_;                  // B*N

    // K0: kpv = pv(p_xyz)
    pv_prep<<<B_*N_, 256, 0, stream>>>(p_xyz, v_xyz, Wp1, bp1, lnw, lnb, Wp2, bp2, kpv);
    // K1: kpv += p_features @ Wk + bk ; vv = p_features @ Wv + bv ; q = v_features @ Wq + bq
    gemm_rm<true ><<<dim3(B_*N_/64, 4), 256, 0, stream>>>(p_features, Wk, bk, kpv);
    gemm_rm<false><<<dim3(B_*N_/64, 4), 256, 0, stream>>>(p_features, Wv, bv, vv);
    gemm_rm<false><<<dim3(B_*M_/64, 4), 256, 0, stream>>>(v_features, Wq, bq, q);
    // K2: per-(b,n) softmax stats over m
    col_stats<<<B_*N_/64, 256, 0, stream>>>(kpv, q, cm, ci);
    // K3: out = v_features
    init_out<<<(B_*M_*D_/4)/256, 256, 0, stream>>>(v_features, out);
    // K4: out += softmax_m(q@kpv^T * scale) @ vv   (atomic accumulation over 8 n-splits)
    attn_out<<<B_*NS_*32, 256, 0, stream>>>(q, kpv, vv, cm, ci, out);
}

// Round 2
// 1496.223 us; speedup vs baseline: 1.8964x; 1.8964x over previous
//
#include <hip/hip_runtime.h>
#include <math.h>

namespace {

constexpr int   B_ = 2;
constexpr int   N_ = 16384;
constexpr int   M_ = 2048;
constexpr int   D_ = 256;
constexpr float SCALE_  = 0.0625f;   // 1/sqrt(256)
constexpr float LN_EPS_ = 1e-5f;
constexpr int   NS_  = 8;            // n-splits in attn_out
constexpr int   NPB_ = N_ / NS_;     // 2048 n per block

typedef __bf16 bf16x8 __attribute__((ext_vector_type(8)));
typedef float  f32x16 __attribute__((ext_vector_type(16)));

__device__ inline bf16x8 ld_frag(const unsigned short* p) {
    return __builtin_bit_cast(bf16x8, *reinterpret_cast<const uint4*>(p));
}
__device__ inline void split_bf16(float x, unsigned short& h, unsigned short& l) {
    __bf16 hb = (__bf16)x;
    float  hf = (float)hb;
    __bf16 lb = (__bf16)(x - hf);
    h = __builtin_bit_cast(unsigned short, hb);
    l = __builtin_bit_cast(unsigned short, lb);
}
#define MFMA32(acc, a, b) (acc) = __builtin_amdgcn_mfma_f32_32x32x16_bf16((a), (b), (acc), 0, 0, 0)

// C/D layout for 32x32 MFMA (m74/m101-verified): col = lane&31,
// row = (reg&3) + 8*(reg>>2) + 4*(lane>>5).
__device__ inline int cd_row(int reg, int lane) {
    return (reg & 3) + 8 * (reg >> 2) + 4 * (lane >> 5);
}

// ---------------- P0: W^T hi/lo planes ----------------
// WTh/WTl layout: [mat][c][d], mat in {Q,K,V}, 256x256 each.
__global__ void prep_wt(const float* __restrict__ Wq, const float* __restrict__ Wk,
                        const float* __restrict__ Wv,
                        unsigned short* __restrict__ WTh, unsigned short* __restrict__ WTl) {
    const int mat = blockIdx.x >> 8;
    const int c   = blockIdx.x & 255;
    const int d   = threadIdx.x;
    const float* W = (mat == 0) ? Wq : (mat == 1) ? Wk : Wv;
    unsigned short h, l;
    split_bf16(W[d * D_ + c], h, l);
    const int idx = mat * D_ * D_ + c * D_ + d;
    WTh[idx] = h;
    WTl[idx] = l;
}

// ---------------- P1: hr = relu(LN(|p-v| @ Wp1 + bp1)) ----------------
__global__ void prep_hr(const float* __restrict__ p_xyz, const float* __restrict__ v_xyz,
                        const float* __restrict__ Wp1, const float* __restrict__ bp1,
                        const float* __restrict__ ln_w, const float* __restrict__ ln_b,
                        float4* __restrict__ hr4) {
    const int r = blockIdx.x * 256 + threadIdx.x;
    if (r >= B_ * N_) return;
    const int b = r / N_;
    const float d0 = fabsf(p_xyz[r*3+0] - v_xyz[b*3+0]);
    const float d1 = fabsf(p_xyz[r*3+1] - v_xyz[b*3+1]);
    const float d2 = fabsf(p_xyz[r*3+2] - v_xyz[b*3+2]);
    float h[3];
    #pragma unroll
    for (int j = 0; j < 3; ++j)
        h[j] = d0*Wp1[0*3+j] + d1*Wp1[1*3+j] + d2*Wp1[2*3+j] + bp1[j];
    const float mu = (h[0]+h[1]+h[2]) * (1.0f/3.0f);
    const float e0 = h[0]-mu, e1 = h[1]-mu, e2 = h[2]-mu;
    const float var = (e0*e0 + e1*e1 + e2*e2) * (1.0f/3.0f);
    const float inv = rsqrtf(var + LN_EPS_);
    hr4[r] = make_float4(fmaxf(e0*inv*ln_w[0] + ln_b[0], 0.0f),
                         fmaxf(e1*inv*ln_w[1] + ln_b[1], 0.0f),
                         fmaxf(e2*inv*ln_w[2] + ln_b[2], 0.0f), 0.0f);
}

// ---------------- K1: projection GEMM (MFMA, hi/lo split) ----------------
// out[row][c] = in[row][:] @ W[:][c] + bias[c] (+ pv for K), written as hi/lo
// bf16 planes. MODE 0=Q (row-major out), 1=K (row-major + pv), 2=V (out
// transposed to [b][c][n] planes via LDS).
// Block: 64 rows x 256 c, 4 waves: wr = w&1 (row half), wc = w>>1 (c half).
template<int MODE>
__global__ void gemm_qkv(const float* __restrict__ in,
                         const unsigned short* __restrict__ WTh_m,
                         const unsigned short* __restrict__ WTl_m,
                         const float* __restrict__ bias,
                         const float4* __restrict__ hr4,
                         const float* __restrict__ Wp2, const float* __restrict__ bp2,
                         unsigned short* __restrict__ outh, unsigned short* __restrict__ outl) {
    __shared__ uint32_t tbuf[4][32 * 36];   // MODE 2 transpose staging
    const int tid  = threadIdx.x;
    const int lane = tid & 63;
    const int w    = tid >> 6;
    const int wr   = w & 1;
    const int wc   = w >> 1;
    const int lane31 = lane & 31;
    const int khalf  = (lane >> 5) * 8;
    const int r0 = blockIdx.x * 64;
    const int rowA = r0 + wr * 32 + lane31;

    const float* ap = in + (size_t)rowA * D_ + khalf;
    const unsigned short* bph[4];
    const unsigned short* bpl[4];
    #pragma unroll
    for (int t = 0; t < 4; ++t) {
        const int cc = wc * 128 + t * 32 + lane31;
        bph[t] = WTh_m + (size_t)cc * D_ + khalf;
        bpl[t] = WTl_m + (size_t)cc * D_ + khalf;
    }

    f32x16 acc[4];
    #pragma unroll
    for (int t = 0; t < 4; ++t) acc[t] = (f32x16)0.0f;

    union U8 { unsigned short u[8]; bf16x8 v; };

    #pragma unroll 4
    for (int ks = 0; ks < 16; ++ks) {
        const float4 f0 = *reinterpret_cast<const float4*>(ap + ks*16);
        const float4 f1 = *reinterpret_cast<const float4*>(ap + ks*16 + 4);
        const float xs[8] = {f0.x, f0.y, f0.z, f0.w, f1.x, f1.y, f1.z, f1.w};
        U8 ah, al;
        #pragma unroll
        for (int j = 0; j < 8; ++j) split_bf16(xs[j], ah.u[j], al.u[j]);
        #pragma unroll
        for (int t = 0; t < 4; ++t) {
            const bf16x8 bh = ld_frag(bph[t] + ks*16);
            const bf16x8 bl = ld_frag(bpl[t] + ks*16);
            MFMA32(acc[t], ah.v, bh);
            MFMA32(acc[t], ah.v, bl);
            MFMA32(acc[t], al.v, bh);
        }
    }

    // per-tile column constants
    float biasc[4], w0c[4], w1c[4], w2c[4], b2c[4];
    #pragma unroll
    for (int t = 0; t < 4; ++t) {
        const int cc = wc * 128 + t * 32 + lane31;
        biasc[t] = bias[cc];
        if (MODE == 1) {
            w0c[t] = Wp2[0*D_ + cc];
            w1c[t] = Wp2[1*D_ + cc];
            w2c[t] = Wp2[2*D_ + cc];
            b2c[t] = bp2[cc];
        }
    }

    if (MODE != 2) {
        #pragma unroll
        for (int r = 0; r < 16; ++r) {
            const int row = r0 + wr * 32 + cd_row(r, lane);
            float4 h4 = make_float4(0,0,0,0);
            if (MODE == 1) h4 = hr4[row];
            #pragma unroll
            for (int t = 0; t < 4; ++t) {
                const int cc = wc * 128 + t * 32 + lane31;
                float v = acc[t][r] + biasc[t];
                if (MODE == 1) v += h4.x*w0c[t] + h4.y*w1c[t] + h4.z*w2c[t] + b2c[t];
                unsigned short h, l;
                split_bf16(v, h, l);
                outh[(size_t)row * D_ + cc] = h;
                outl[(size_t)row * D_ + cc] = l;
            }
        }
    } else {
        // V: transpose through LDS to [b][c][n] planes
        const int bb   = r0 / N_;
        const int nloc = r0 % N_;
        #pragma unroll
        for (int t = 0; t < 4; ++t) {
            __syncthreads();
            #pragma unroll
            for (int r = 0; r < 16; ++r) {
                const int rowl = cd_row(r, lane);
                unsigned short h, l;
                split_bf16(acc[t][r] + biasc[t], h, l);
                tbuf[w][lane31 * 36 + rowl] = (uint32_t)h | ((uint32_t)l << 16);
            }
            __syncthreads();
            const int cl = lane >> 1;
            const int nh = (lane & 1) * 16;
            const int cglob = wc * 128 + t * 32 + cl;
            const size_t gb = ((size_t)(bb * D_ + cglob)) * N_ + nloc + wr * 32 + nh;
            #pragma unroll
            for (int j = 0; j < 16; ++j) {
                const uint32_t u = tbuf[w][cl * 36 + nh + j];
                outh[gb + j] = (unsigned short)(u & 0xffff);
                outl[gb + j] = (unsigned short)(u >> 16);
            }
        }
    }
}

// ---------------- K2: per-(b,n) softmax stats over m (MFMA) ----------------
// Block: 128 n (4 waves x 32 n), loops all M in 32-row chunks.
__global__ void col_stats(const unsigned short* __restrict__ qh, const unsigned short* __restrict__ ql,
                          const unsigned short* __restrict__ kh, const unsigned short* __restrict__ kl,
                          float* __restrict__ cmax, float* __restrict__ cinv) {
    const int tid  = threadIdx.x;
    const int lane = tid & 63;
    const int w    = tid >> 6;
    const int lane31 = lane & 31;
    const int khalf  = (lane >> 5) * 8;
    const int nfl = blockIdx.x * 128 + w * 32 + lane31;   // flat n (this lane's column)
    const int b   = (blockIdx.x * 128) / N_;

    const unsigned short* kph = kh + (size_t)nfl * D_ + khalf;
    const unsigned short* kpl = kl + (size_t)nfl * D_ + khalf;

    float cm = -INFINITY, cs = 0.0f;

    for (int mt = 0; mt < M_ / 32; ++mt) {
        const size_t qrow = (size_t)(b * M_ + mt * 32 + lane31) * D_ + khalf;
        f32x16 s = (f32x16)0.0f;
        #pragma unroll 4
        for (int ks = 0; ks < 16; ++ks) {
            const bf16x8 ah = ld_frag(qh + qrow + ks*16);
            const bf16x8 al = ld_frag(ql + qrow + ks*16);
            const bf16x8 bh = ld_frag(kph + ks*16);
            const bf16x8 bl = ld_frag(kpl + ks*16);
            MFMA32(s, ah, bh);
            MFMA32(s, ah, bl);
            MFMA32(s, al, bh);
        }
        float sm[16];
        float tmax = -INFINITY;
        #pragma unroll
        for (int r = 0; r < 16; ++r) { sm[r] = s[r] * SCALE_; tmax = fmaxf(tmax, sm[r]); }
        const float nm = fmaxf(cm, tmax);
        const float f  = __expf(cm - nm);      // first chunk: exp(-inf) = 0
        float ts = 0.0f;
        #pragma unroll
        for (int r = 0; r < 16; ++r) ts += __expf(sm[r] - nm);
        cs = cs * f + ts;
        cm = nm;
    }
    // combine the two m-halves (lane ^ 32 holds the other 16 rows per tile)
    const float ocm = __shfl_xor(cm, 32, 64);
    const float ocs = __shfl_xor(cs, 32, 64);
    const float nm  = fmaxf(cm, ocm);
    const float tot = cs * __expf(cm - nm) + ocs * __expf(ocm - nm);
    if (lane < 32) {
        cmax[nfl] = nm;
        cinv[nfl] = 1.0f / tot;
    }
}

// ---------------- K3: out = v_features ----------------
__global__ void init_out(const float* __restrict__ src, float* __restrict__ dst) {
    const int i = blockIdx.x * blockDim.x + threadIdx.x;
    reinterpret_cast<float4*>(dst)[i] = reinterpret_cast<const float4*>(src)[i];
}

// ---------------- K4: out += softmax-weighted V (MFMA) ----------------
// Block: 64 m x 256 d output tile, n-split NS_. Per 64-n chunk:
//  phase A: S = q @ kpv^T (4 waves = 2x2 (wm,wh) quadrants of 64x64)
//  exp -> P hi/lo planes in LDS (C-layout write, stride 72 = 16B aligned)
//  phase B: out += P @ V (wave (wm,wh): rows wm*32, d-range wh*128)
__global__ void attn_out(const unsigned short* __restrict__ qh, const unsigned short* __restrict__ ql,
                         const unsigned short* __restrict__ kh, const unsigned short* __restrict__ kl,
                         const unsigned short* __restrict__ vTh, const unsigned short* __restrict__ vTl,
                         const float* __restrict__ cmax, const float* __restrict__ cinv,
                         float* __restrict__ out) {
    __shared__ unsigned short Ph[64 * 72];
    __shared__ unsigned short Pl[64 * 72];
    const int tid  = threadIdx.x;
    const int lane = tid & 63;
    const int w    = tid >> 6;
    const int wm   = w & 1;
    const int wh   = w >> 1;
    const int lane31 = lane & 31;
    const int khalf  = (lane >> 5) * 8;

    // XCD swizzle: blocks sharing (b,ns) (same K/V slice) land on same XCD.
    const int bid = blockIdx.x;
    const int mt  = bid >> 4;        // 0..31
    const int grp = bid & 15;        // (b, ns)
    const int b   = grp >> 3;
    const int ns  = grp & 7;
    const int m0  = mt * 64;

    const size_t qrow = (size_t)(b * M_ + m0 + wm * 32 + lane31) * D_ + khalf;

    f32x16 oacc[4];
    #pragma unroll
    for (int t = 0; t < 4; ++t) oacc[t] = (f32x16)0.0f;

    for (int c = 0; c < NPB_ / 64; ++c) {
        const int nbase = ns * NPB_ + c * 64;            // within-batch n base
        // ---- phase A: S quadrant (wm, wh) ----
        const size_t krow = (size_t)(b * N_ + nbase + wh * 32 + lane31) * D_ + khalf;
        f32x16 s = (f32x16)0.0f;
        #pragma unroll 4
        for (int ks = 0; ks < 16; ++ks) {
            const bf16x8 ah = ld_frag(qh + qrow + ks*16);
            const bf16x8 al = ld_frag(ql + qrow + ks*16);
            const bf16x8 bh = ld_frag(kh + krow + ks*16);
            const bf16x8 bl = ld_frag(kl + krow + ks*16);
            MFMA32(s, ah, bh);
            MFMA32(s, ah, bl);
            MFMA32(s, al, bh);
        }
        const int ncol = nbase + wh * 32 + lane31;
        const float cmv = cmax[b * N_ + ncol];
        const float civ = cinv[b * N_ + ncol];
        #pragma unroll
        for (int r = 0; r < 16; ++r) {
            const float p = __expf(s[r] * SCALE_ - cmv) * civ;
            unsigned short hph, hpl;
            split_bf16(p, hph, hpl);
            const int row = wm * 32 + cd_row(r, lane);
            const int col = wh * 32 + lane31;
            Ph[row * 72 + col] = hph;
            Pl[row * 72 + col] = hpl;
        }
        __syncthreads();
        // ---- phase B: out(rows wm*32, cols wh*128) += P @ V ----
        const unsigned short* prh = Ph + (wm * 32 + lane31) * 72 + khalf;
        const unsigned short* prl = Pl + (wm * 32 + lane31) * 72 + khalf;
        const size_t vb = ((size_t)(b * D_ + wh * 128 + lane31)) * N_ + nbase + khalf;
        #pragma unroll
        for (int k2 = 0; k2 < 4; ++k2) {
            const bf16x8 a2h = ld_frag(prh + k2*16);
            const bf16x8 a2l = ld_frag(prl + k2*16);
            #pragma unroll
            for (int t = 0; t < 4; ++t) {
                const size_t vo = vb + (size_t)t * 32 * N_ + k2 * 16;
                const bf16x8 b2h = ld_frag(vTh + vo);
                const bf16x8 b2l = ld_frag(vTl + vo);
                MFMA32(oacc[t], a2h, b2h);
                MFMA32(oacc[t], a2h, b2l);
                MFMA32(oacc[t], a2l, b2h);
            }
        }
        __syncthreads();
    }
    // epilogue: atomic accumulate
    #pragma unroll
    for (int t = 0; t < 4; ++t) {
        #pragma unroll
        for (int r = 0; r < 16; ++r) {
            const int row  = m0 + wm * 32 + cd_row(r, lane);
            const int dcol = wh * 128 + t * 32 + lane31;
            atomicAdd(&out[((size_t)(b * M_ + row)) * D_ + dcol], oacc[t][r]);
        }
    }
}

} // anonymous namespace

extern "C" void kernel_launch(void* const* d_in, const int* in_sizes, int n_in,
                              void* d_out, int out_size, void* d_ws, size_t ws_size,
                              hipStream_t stream) {
    const float* p_xyz      = (const float*)d_in[0];
    const float* v_xyz      = (const float*)d_in[1];
    const float* p_features = (const float*)d_in[2];
    const float* v_features = (const float*)d_in[3];
    const float* Wq  = (const float*)d_in[4];
    const float* bq  = (const float*)d_in[5];
    const float* Wk  = (const float*)d_in[6];
    const float* bk  = (const float*)d_in[7];
    const float* Wv  = (const float*)d_in[8];
    const float* bv  = (const float*)d_in[9];
    const float* Wp1 = (const float*)d_in[10];
    const float* bp1 = (const float*)d_in[11];
    const float* lnw = (const float*)d_in[12];
    const float* lnb = (const float*)d_in[13];
    const float* Wp2 = (const float*)d_in[14];
    const float* bp2 = (const float*)d_in[15];
    float* out = (float*)d_out;

    // ---- workspace carve-up (all 256B-aligned), total ~69.5 MB ----
    char* p = (char*)d_ws;
    auto alloc = [&](size_t bytes) {
        void* r = (void*)p;
        p += (bytes + 255) & ~(size_t)255;
        return r;
    };
    unsigned short* qh  = (unsigned short*)alloc((size_t)B_*M_*D_*2);
    unsigned short* ql  = (unsigned short*)alloc((size_t)B_*M_*D_*2);
    unsigned short* kh  = (unsigned short*)alloc((size_t)B_*N_*D_*2);
    unsigned short* kl  = (unsigned short*)alloc((size_t)B_*N_*D_*2);
    unsigned short* vTh = (unsigned short*)alloc((size_t)B_*N_*D_*2);
    unsigned short* vTl = (unsigned short*)alloc((size_t)B_*N_*D_*2);
    unsigned short* WTh = (unsigned short*)alloc((size_t)3*D_*D_*2);
    unsigned short* WTl = (unsigned short*)alloc((size_t)3*D_*D_*2);
    float4*         hr4 = (float4*)alloc((size_t)B_*N_*16);
    float*          cm  = (float*)alloc((size_t)B_*N_*4);
    float*          ci  = (float*)alloc((size_t)B_*N_*4);

    // P0/P1: weight transpose + pv front half
    prep_wt<<<3*256, 256, 0, stream>>>(Wq, Wk, Wv, WTh, WTl);
    prep_hr<<<(B_*N_)/256, 256, 0, stream>>>(p_xyz, v_xyz, Wp1, bp1, lnw, lnb, hr4);
    // K1: projections (MFMA hi/lo)
    gemm_qkv<0><<<(B_*M_)/64, 256, 0, stream>>>(v_features, WTh + 0*D_*D_, WTl + 0*D_*D_,
                                                bq, hr4, Wp2, bp2, qh, ql);
    gemm_qkv<1><<<(B_*N_)/64, 256, 0, stream>>>(p_features, WTh + 1*D_*D_, WTl + 1*D_*D_,
                                                bk, hr4, Wp2, bp2, kh, kl);
    gemm_qkv<2><<<(B_*N_)/64, 256, 0, stream>>>(p_features, WTh + 2*D_*D_, WTl + 2*D_*D_,
                                                bv, hr4, Wp2, bp2, vTh, vTl);
    // K2: softmax column stats (over m)
    col_stats<<<(B_*N_)/128, 256, 0, stream>>>(qh, ql, kh, kl, cm, ci);
    // K3: out = v_features
    init_out<<<(B_*M_*D_/4)/256, 256, 0, stream>>>(v_features, out);
    // K4: out += softmax_m(q@kpv^T * scale) @ v
    attn_out<<<B_*NS_*(M_/64), 256, 0, stream>>>(qh, ql, kh, kl, vTh, vTl, cm, ci, out);
}

// Round 3
// 828.899 us; speedup vs baseline: 3.4232x; 1.8051x over previous
//
#include <hip/hip_runtime.h>
#include <math.h>

namespace {

constexpr int   B_ = 2;
constexpr int   N_ = 16384;
constexpr int   M_ = 2048;
constexpr int   D_ = 256;
constexpr float SCALE_  = 0.0625f;   // 1/sqrt(256)
constexpr float LN_EPS_ = 1e-5f;
constexpr int   NS_  = 16;           // n-splits in attn_out
constexpr int   NPB_ = N_ / NS_;     // 1024 n per block

typedef __bf16 bf16x8 __attribute__((ext_vector_type(8)));
typedef float  f32x16 __attribute__((ext_vector_type(16)));

__device__ inline bf16x8 as_frag(uint4 u) { return __builtin_bit_cast(bf16x8, u); }
__device__ inline void split_bf16(float x, unsigned short& h, unsigned short& l) {
    __bf16 hb = (__bf16)x;
    float  hf = (float)hb;
    __bf16 lb = (__bf16)(x - hf);
    h = __builtin_bit_cast(unsigned short, hb);
    l = __builtin_bit_cast(unsigned short, lb);
}
__device__ inline uint4 pack8(const unsigned short v[8]) {
    return make_uint4((uint32_t)v[0] | ((uint32_t)v[1] << 16),
                      (uint32_t)v[2] | ((uint32_t)v[3] << 16),
                      (uint32_t)v[4] | ((uint32_t)v[5] << 16),
                      (uint32_t)v[6] | ((uint32_t)v[7] << 16));
}
#define MFMA32(acc, a, b) (acc) = __builtin_amdgcn_mfma_f32_32x32x16_bf16((a), (b), (acc), 0, 0, 0)

// C/D layout for 32x32 MFMA: col = lane&31, row = (reg&3)+8*(reg>>2)+4*(lane>>5)
__device__ inline int cd_row(int reg, int lane) {
    return (reg & 3) + 8 * (reg >> 2) + 4 * (lane >> 5);
}

// Packet layout (all bf16 operand planes):
//   A/B-fragment packet p = tile32*16 + ks ; element = packet*64 + lane (uint4)
//   lane holds  X[tile32*32 + (lane&31)][ks*16 + (lane>>5)*8 + j]  j=0..7
// V packets (PV B-operand, contraction over n):
//   packet = gg*8 + dt (gg = flat_n/16, dt = d/32); lane holds
//   V[gg*16 + (lane>>5)*8 + j][dt*32 + (lane&31)]

// ---------------- P0: W -> B-operand packet planes ----------------
// wph/wpl: [mat][ctile(8)][ks(16)] packets; grid 3*8 blocks x 256
__global__ void prep_wt(const float* __restrict__ Wq, const float* __restrict__ Wk,
                        const float* __restrict__ Wv,
                        uint4* __restrict__ wph, uint4* __restrict__ wpl) {
    __shared__ uint32_t ldb[256 * 33];
    const int mat = blockIdx.x >> 3;
    const int Tc  = blockIdx.x & 7;
    const float* W = (mat == 0) ? Wq : (mat == 1) ? Wk : Wv;
    const int d = threadIdx.x;
    #pragma unroll
    for (int c = 0; c < 32; c += 4) {
        const float4 v = *reinterpret_cast<const float4*>(&W[d * D_ + Tc * 32 + c]);
        const float xs[4] = {v.x, v.y, v.z, v.w};
        #pragma unroll
        for (int i = 0; i < 4; ++i) {
            unsigned short h, l;
            split_bf16(xs[i], h, l);
            ldb[d * 33 + c + i] = (uint32_t)h | ((uint32_t)l << 16);
        }
    }
    __syncthreads();
    const int lane = threadIdx.x & 63;
    const int pg   = threadIdx.x >> 6;
    #pragma unroll
    for (int kq = 0; kq < 4; ++kq) {
        const int ks = pg * 4 + kq;
        unsigned short hh[8], ll[8];
        #pragma unroll
        for (int j = 0; j < 8; ++j) {
            const uint32_t u = ldb[(ks * 16 + (lane >> 5) * 8 + j) * 33 + (lane & 31)];
            hh[j] = (unsigned short)(u & 0xffff);
            ll[j] = (unsigned short)(u >> 16);
        }
        const size_t o = ((size_t)((mat * 8 + Tc) * 16 + ks)) * 64 + lane;
        wph[o] = pack8(hh);
        wpl[o] = pack8(ll);
    }
}

// ---------------- P1: hr = relu(LN(|p-v| @ Wp1 + bp1)) ----------------
__global__ void prep_hr(const float* __restrict__ p_xyz, const float* __restrict__ v_xyz,
                        const float* __restrict__ Wp1, const float* __restrict__ bp1,
                        const float* __restrict__ ln_w, const float* __restrict__ ln_b,
                        float4* __restrict__ hr4) {
    const int r = blockIdx.x * 256 + threadIdx.x;
    if (r >= B_ * N_) return;
    const int b = r / N_;
    const float d0 = fabsf(p_xyz[r*3+0] - v_xyz[b*3+0]);
    const float d1 = fabsf(p_xyz[r*3+1] - v_xyz[b*3+1]);
    const float d2 = fabsf(p_xyz[r*3+2] - v_xyz[b*3+2]);
    float h[3];
    #pragma unroll
    for (int j = 0; j < 3; ++j)
        h[j] = d0*Wp1[0*3+j] + d1*Wp1[1*3+j] + d2*Wp1[2*3+j] + bp1[j];
    const float mu = (h[0]+h[1]+h[2]) * (1.0f/3.0f);
    const float e0 = h[0]-mu, e1 = h[1]-mu, e2 = h[2]-mu;
    const float var = (e0*e0 + e1*e1 + e2*e2) * (1.0f/3.0f);
    const float inv = rsqrtf(var + LN_EPS_);
    hr4[r] = make_float4(fmaxf(e0*inv*ln_w[0] + ln_b[0], 0.0f),
                         fmaxf(e1*inv*ln_w[1] + ln_b[1], 0.0f),
                         fmaxf(e2*inv*ln_w[2] + ln_b[2], 0.0f), 0.0f);
}

// ---------------- K1: projection GEMM -> packet-layout hi/lo outputs ----------------
// MODE 0=Q, 1=K(+pv), 2=V (V packets for PV consumption)
template<int MODE>
__global__ void gemm_qkv(const float* __restrict__ in,
                         const uint4* __restrict__ wph, const uint4* __restrict__ wpl,
                         const float* __restrict__ bias,
                         const float4* __restrict__ hr4,
                         const float* __restrict__ Wp2, const float* __restrict__ bp2,
                         uint4* __restrict__ oh, uint4* __restrict__ ol) {
    __shared__ uint32_t tb[4][32 * 33];
    const int tid  = threadIdx.x;
    const int lane = tid & 63;
    const int w    = tid >> 6;
    const int wr   = w & 1;
    const int wc   = w >> 1;
    const int lane31 = lane & 31;
    const int Trow = blockIdx.x * 2 + wr;                 // 32-row tile index (flat)
    const int rowA = Trow * 32 + lane31;
    const float* ap = in + (size_t)rowA * D_ + (lane >> 5) * 8;

    f32x16 acc[4];
    #pragma unroll
    for (int t = 0; t < 4; ++t) acc[t] = (f32x16)0.0f;

    union U8 { unsigned short u[8]; bf16x8 v; };
    #pragma unroll 4
    for (int ks = 0; ks < 16; ++ks) {
        const float4 f0 = *reinterpret_cast<const float4*>(ap + ks*16);
        const float4 f1 = *reinterpret_cast<const float4*>(ap + ks*16 + 4);
        const float xs[8] = {f0.x, f0.y, f0.z, f0.w, f1.x, f1.y, f1.z, f1.w};
        U8 ah, al;
        #pragma unroll
        for (int j = 0; j < 8; ++j) split_bf16(xs[j], ah.u[j], al.u[j]);
        #pragma unroll
        for (int t = 0; t < 4; ++t) {
            const size_t wb = ((size_t)((wc * 4 + t) * 16 + ks)) * 64 + lane;
            const bf16x8 bh = as_frag(wph[wb]);
            const bf16x8 bl = as_frag(wpl[wb]);
            MFMA32(acc[t], ah.v, bh);
            MFMA32(acc[t], ah.v, bl);
            MFMA32(acc[t], al.v, bh);
        }
    }

    float biasc[4], w0c[4], w1c[4], w2c[4], b2c[4];
    #pragma unroll
    for (int t = 0; t < 4; ++t) {
        const int cc = wc * 128 + t * 32 + lane31;
        biasc[t] = bias[cc];
        if (MODE == 1) {
            w0c[t] = Wp2[0*D_ + cc]; w1c[t] = Wp2[1*D_ + cc];
            w2c[t] = Wp2[2*D_ + cc]; b2c[t] = bp2[cc];
        }
    }
    float4 hv[16];
    if (MODE == 1) {
        #pragma unroll
        for (int r = 0; r < 16; ++r) hv[r] = hr4[Trow * 32 + cd_row(r, lane)];
    }

    #pragma unroll
    for (int t = 0; t < 4; ++t) {
        #pragma unroll
        for (int r = 0; r < 16; ++r) {
            float v = acc[t][r] + biasc[t];
            if (MODE == 1) v += hv[r].x*w0c[t] + hv[r].y*w1c[t] + hv[r].z*w2c[t] + b2c[t];
            unsigned short h, l;
            split_bf16(v, h, l);
            tb[w][cd_row(r, lane) * 33 + lane31] = (uint32_t)h | ((uint32_t)l << 16);
        }
        if (MODE != 2) {
            // A/B-fragment packets: 2 per 32-col tile
            #pragma unroll
            for (int p = 0; p < 2; ++p) {
                const int ks = wc * 8 + t * 2 + p;
                unsigned short hh[8], ll[8];
                #pragma unroll
                for (int j = 0; j < 8; ++j) {
                    const uint32_t u = tb[w][lane31 * 33 + p * 16 + (lane >> 5) * 8 + j];
                    hh[j] = (unsigned short)(u & 0xffff);
                    ll[j] = (unsigned short)(u >> 16);
                }
                const size_t o = ((size_t)(Trow * 16 + ks)) * 64 + lane;
                oh[o] = pack8(hh);
                ol[o] = pack8(ll);
            }
        } else {
            // V packets: 2 n-halves per tile
            #pragma unroll
            for (int h16 = 0; h16 < 2; ++h16) {
                const int gg = Trow * 2 + h16;            // flat_n/16
                const int dt = wc * 4 + t;
                unsigned short hh[8], ll[8];
                #pragma unroll
                for (int j = 0; j < 8; ++j) {
                    const uint32_t u = tb[w][(h16 * 16 + (lane >> 5) * 8 + j) * 33 + lane31];
                    hh[j] = (unsigned short)(u & 0xffff);
                    ll[j] = (unsigned short)(u >> 16);
                }
                const size_t o = ((size_t)(gg * 8 + dt)) * 64 + lane;
                oh[o] = pack8(hh);
                ol[o] = pack8(ll);
            }
        }
    }
}

// ---------------- K2: per-(b,n) softmax stats over m ----------------
// Block: 64 n (2 tiles x wn), K stationary in registers, m split across wm.
__global__ void col_stats(const uint4* __restrict__ qh, const uint4* __restrict__ ql,
                          const uint4* __restrict__ kh, const uint4* __restrict__ kl,
                          float* __restrict__ cmax, float* __restrict__ cinv) {
    __shared__ float mb[4][32], sb[4][32];
    const int tid  = threadIdx.x;
    const int lane = tid & 63;
    const int w    = tid >> 6;
    const int wn   = w & 1;
    const int wm   = w >> 1;
    const int nflat = blockIdx.x * 64 + wn * 32;          // this wave's n-tile base
    const int b     = (blockIdx.x * 64) / N_;
    const int Tk    = blockIdx.x * 2 + wn;

    uint4 kfh[16], kfl[16];
    #pragma unroll
    for (int ks = 0; ks < 16; ++ks) {
        const size_t o = ((size_t)(Tk * 16 + ks)) * 64 + lane;
        kfh[ks] = kh[o];
        kfl[ks] = kl[o];
    }

    float cm = -INFINITY, cs = 0.0f;
    for (int mt = wm; mt < M_ / 32; mt += 2) {
        const size_t qb = ((size_t)((b * (M_/32) + mt) * 16)) * 64 + lane;
        f32x16 s = (f32x16)0.0f;
        #pragma unroll 8
        for (int ks = 0; ks < 16; ++ks) {
            const bf16x8 ah = as_frag(qh[qb + ks * 64]);
            const bf16x8 al = as_frag(ql[qb + ks * 64]);
            MFMA32(s, ah, as_frag(kfh[ks]));
            MFMA32(s, ah, as_frag(kfl[ks]));
            MFMA32(s, al, as_frag(kfh[ks]));
        }
        float sm[16], tmax = -INFINITY;
        #pragma unroll
        for (int r = 0; r < 16; ++r) { sm[r] = s[r] * SCALE_; tmax = fmaxf(tmax, sm[r]); }
        const float nm = fmaxf(cm, tmax);
        const float f  = __expf(cm - nm);
        float ts = 0.0f;
        #pragma unroll
        for (int r = 0; r < 16; ++r) ts += __expf(sm[r] - nm);
        cs = cs * f + ts;
        cm = nm;
    }
    // merge lane ^ 32 (other row-half of same n-column)
    const float ocm = __shfl_xor(cm, 32, 64);
    const float ocs = __shfl_xor(cs, 32, 64);
    const float nm1 = fmaxf(cm, ocm);
    const float tt1 = cs * __expf(cm - nm1) + ocs * __expf(ocm - nm1);
    if (lane < 32) { mb[w][lane] = nm1; sb[w][lane] = tt1; }
    __syncthreads();
    if (wm == 0 && lane < 32) {
        const float m2 = mb[w + 2][lane], s2 = sb[w + 2][lane];
        const float mm = fmaxf(nm1, m2);
        const float tt = tt1 * __expf(nm1 - mm) + s2 * __expf(m2 - mm);
        cmax[nflat + lane] = mm;
        cinv[nflat + lane] = 1.0f / tt;
    }
}

// ---------------- K3: out = v_features ----------------
__global__ void init_out(const float* __restrict__ src, float* __restrict__ dst) {
    const int i = blockIdx.x * blockDim.x + threadIdx.x;
    reinterpret_cast<float4*>(dst)[i] = reinterpret_cast<const float4*>(src)[i];
}

// ---------------- K4: out += softmax-weighted V ----------------
__global__ void attn_out(const uint4* __restrict__ qh, const uint4* __restrict__ ql,
                         const uint4* __restrict__ kh, const uint4* __restrict__ kl,
                         const uint4* __restrict__ vh, const uint4* __restrict__ vl,
                         const float* __restrict__ cmax, const float* __restrict__ cinv,
                         float* __restrict__ out) {
    __shared__ unsigned short Ph[64 * 72];
    __shared__ unsigned short Pl[64 * 72];
    const int tid  = threadIdx.x;
    const int lane = tid & 63;
    const int w    = tid >> 6;
    const int wm   = w & 1;
    const int wh   = w >> 1;
    const int lane31 = lane & 31;
    const int kh8    = (lane >> 5) * 8;

    // bid = low3 + 8*(mt*4 + ghi): all 32 m-tiles of group g share XCD (bid%8)
    const int bid  = blockIdx.x;
    const int low3 = bid & 7;
    const int rest = bid >> 3;
    const int ghi  = rest & 3;
    const int mt   = rest >> 2;
    const int g    = ghi * 8 + low3;
    const int b    = g >> 4;
    const int ns   = g & 15;
    const int m0   = mt * 64;

    const size_t qb = ((size_t)(((b * M_ + m0) >> 5) + wm) * 16) * 64 + lane;

    f32x16 oacc[4];
    #pragma unroll
    for (int t = 0; t < 4; ++t) oacc[t] = (f32x16)0.0f;

    for (int c = 0; c < NPB_ / 64; ++c) {
        const int nbase = ns * NPB_ + c * 64;
        // ---- phase A: S quadrant (wm rows, wh n-cols) ----
        const size_t kb = ((size_t)(((b * N_ + nbase) >> 5) + wh) * 16) * 64 + lane;
        f32x16 s = (f32x16)0.0f;
        #pragma unroll 8
        for (int ks = 0; ks < 16; ++ks) {
            const bf16x8 ah = as_frag(qh[qb + ks * 64]);
            const bf16x8 al = as_frag(ql[qb + ks * 64]);
            const bf16x8 bh = as_frag(kh[kb + ks * 64]);
            const bf16x8 bl = as_frag(kl[kb + ks * 64]);
            MFMA32(s, ah, bh);
            MFMA32(s, ah, bl);
            MFMA32(s, al, bh);
        }
        const int ncol = nbase + wh * 32 + lane31;
        const float cmv = cmax[b * N_ + ncol];
        const float civ = cinv[b * N_ + ncol];
        #pragma unroll
        for (int r = 0; r < 16; ++r) {
            const float p = __expf(s[r] * SCALE_ - cmv) * civ;
            unsigned short hph, hpl;
            split_bf16(p, hph, hpl);
            const int row = wm * 32 + cd_row(r, lane);
            const int col = wh * 32 + lane31;
            Ph[row * 72 + col] = hph;
            Pl[row * 72 + col] = hpl;
        }
        __syncthreads();
        // ---- phase B: oacc += P @ V ----
        const unsigned short* prh = Ph + (wm * 32 + lane31) * 72 + kh8;
        const unsigned short* prl = Pl + (wm * 32 + lane31) * 72 + kh8;
        const size_t vb0 = ((size_t)((b * N_ + nbase) >> 4)) * 8 * 64;
        #pragma unroll
        for (int k2 = 0; k2 < 4; ++k2) {
            const bf16x8 a2h = as_frag(*reinterpret_cast<const uint4*>(prh + k2 * 16));
            const bf16x8 a2l = as_frag(*reinterpret_cast<const uint4*>(prl + k2 * 16));
            #pragma unroll
            for (int t = 0; t < 4; ++t) {
                const size_t vo = vb0 + ((size_t)(k2 * 8 + wh * 4 + t)) * 64 + lane;
                const bf16x8 b2h = as_frag(vh[vo]);
                const bf16x8 b2l = as_frag(vl[vo]);
                MFMA32(oacc[t], a2h, b2h);
                MFMA32(oacc[t], a2h, b2l);
                MFMA32(oacc[t], a2l, b2h);
            }
        }
        __syncthreads();
    }
    #pragma unroll
    for (int t = 0; t < 4; ++t) {
        #pragma unroll
        for (int r = 0; r < 16; ++r) {
            const int row  = m0 + wm * 32 + cd_row(r, lane);
            const int dcol = wh * 128 + t * 32 + lane31;
            atomicAdd(&out[((size_t)(b * M_ + row)) * D_ + dcol], oacc[t][r]);
        }
    }
}

} // anonymous namespace

extern "C" void kernel_launch(void* const* d_in, const int* in_sizes, int n_in,
                              void* d_out, int out_size, void* d_ws, size_t ws_size,
                              hipStream_t stream) {
    const float* p_xyz      = (const float*)d_in[0];
    const float* v_xyz      = (const float*)d_in[1];
    const float* p_features = (const float*)d_in[2];
    const float* v_features = (const float*)d_in[3];
    const float* Wq  = (const float*)d_in[4];
    const float* bq  = (const float*)d_in[5];
    const float* Wk  = (const float*)d_in[6];
    const float* bk  = (const float*)d_in[7];
    const float* Wv  = (const float*)d_in[8];
    const float* bv  = (const float*)d_in[9];
    const float* Wp1 = (const float*)d_in[10];
    const float* bp1 = (const float*)d_in[11];
    const float* lnw = (const float*)d_in[12];
    const float* lnb = (const float*)d_in[13];
    const float* Wp2 = (const float*)d_in[14];
    const float* bp2 = (const float*)d_in[15];
    float* out = (float*)d_out;

    // ---- workspace carve-up (256B aligned), ~70.5 MB ----
    char* p = (char*)d_ws;
    auto alloc = [&](size_t bytes) {
        void* r = (void*)p;
        p += (bytes + 255) & ~(size_t)255;
        return r;
    };
    uint4* qh  = (uint4*)alloc((size_t)B_*M_*D_*2);   // bf16 hi plane, packet order
    uint4* ql  = (uint4*)alloc((size_t)B_*M_*D_*2);
    uint4* kh  = (uint4*)alloc((size_t)B_*N_*D_*2);
    uint4* kl  = (uint4*)alloc((size_t)B_*N_*D_*2);
    uint4* vh  = (uint4*)alloc((size_t)B_*N_*D_*2);
    uint4* vl  = (uint4*)alloc((size_t)B_*N_*D_*2);
    uint4* wph = (uint4*)alloc((size_t)3*D_*D_*2);
    uint4* wpl = (uint4*)alloc((size_t)3*D_*D_*2);
    float4* hr4 = (float4*)alloc((size_t)B_*N_*16);
    float*  cm  = (float*)alloc((size_t)B_*N_*4);
    float*  ci  = (float*)alloc((size_t)B_*N_*4);

    constexpr size_t WMAT = (size_t)D_*D_/8;   // uint4 per weight matrix

    prep_wt<<<3*8, 256, 0, stream>>>(Wq, Wk, Wv, wph, wpl);
    prep_hr<<<(B_*N_)/256, 256, 0, stream>>>(p_xyz, v_xyz, Wp1, bp1, lnw, lnb, hr4);

    gemm_qkv<0><<<(B_*M_)/64, 256, 0, stream>>>(v_features, wph + 0*WMAT, wpl + 0*WMAT,
                                                bq, hr4, Wp2, bp2, qh, ql);
    gemm_qkv<1><<<(B_*N_)/64, 256, 0, stream>>>(p_features, wph + 1*WMAT, wpl + 1*WMAT,
                                                bk, hr4, Wp2, bp2, kh, kl);
    gemm_qkv<2><<<(B_*N_)/64, 256, 0, stream>>>(p_features, wph + 2*WMAT, wpl + 2*WMAT,
                                                bv, hr4, Wp2, bp2, vh, vl);

    col_stats<<<(B_*N_)/64, 256, 0, stream>>>(qh, ql, kh, kl, cm, ci);
    init_out<<<(B_*M_*D_/4)/256, 256, 0, stream>>>(v_features, out);
    attn_out<<<B_*NS_*(M_/64), 256, 0, stream>>>(qh, ql, kh, kl, vh, vl, cm, ci, out);
}

// Round 4
// 561.601 us; speedup vs baseline: 5.0525x; 1.4760x over previous
//
#include <hip/hip_runtime.h>
#include <math.h>

namespace {

constexpr int   B_ = 2;
constexpr int   N_ = 16384;
constexpr int   M_ = 2048;
constexpr int   D_ = 256;
constexpr float SCALE_  = 0.0625f;   // 1/sqrt(256)
constexpr float LN_EPS_ = 1e-5f;
constexpr int   NS_  = 16;           // n-splits in attn_out
constexpr int   NPB_ = N_ / NS_;     // 1024 n per block

typedef __bf16 bf16x8 __attribute__((ext_vector_type(8)));
typedef float  f32x16 __attribute__((ext_vector_type(16)));

__device__ inline bf16x8 as_frag(uint4 u) { return __builtin_bit_cast(bf16x8, u); }
__device__ inline void split_bf16(float x, unsigned short& h, unsigned short& l) {
    __bf16 hb = (__bf16)x;
    float  hf = (float)hb;
    __bf16 lb = (__bf16)(x - hf);
    h = __builtin_bit_cast(unsigned short, hb);
    l = __builtin_bit_cast(unsigned short, lb);
}
__device__ inline uint4 pack8(const unsigned short v[8]) {
    return make_uint4((uint32_t)v[0] | ((uint32_t)v[1] << 16),
                      (uint32_t)v[2] | ((uint32_t)v[3] << 16),
                      (uint32_t)v[4] | ((uint32_t)v[5] << 16),
                      (uint32_t)v[6] | ((uint32_t)v[7] << 16));
}
#define MFMA32(acc, a, b) (acc) = __builtin_amdgcn_mfma_f32_32x32x16_bf16((a), (b), (acc), 0, 0, 0)

// C/D layout for 32x32 MFMA: col = lane&31, row = (reg&3)+8*(reg>>2)+4*(lane>>5)
__device__ inline int cd_row(int reg, int lane) {
    return (reg & 3) + 8 * (reg >> 2) + 4 * (lane >> 5);
}

// Packet layout (all bf16 operand planes):
//   A/B-fragment packet p = tile32*16 + ks ; element = packet*64 + lane (uint4)
//   lane holds  X[tile32*32 + (lane&31)][ks*16 + (lane>>5)*8 + j]  j=0..7
// V packets (PV B-operand, contraction over n):
//   packet = gg*8 + dt (gg = flat_n/16, dt = d/32); lane holds
//   V[gg*16 + (lane>>5)*8 + j][dt*32 + (lane&31)]

// ---------------- P0: W -> B-operand packet planes ----------------
__global__ void prep_wt(const float* __restrict__ Wq, const float* __restrict__ Wk,
                        const float* __restrict__ Wv,
                        uint4* __restrict__ wph, uint4* __restrict__ wpl) {
    __shared__ uint32_t ldb[256 * 33];
    const int mat = blockIdx.x >> 3;
    const int Tc  = blockIdx.x & 7;
    const float* W = (mat == 0) ? Wq : (mat == 1) ? Wk : Wv;
    const int d = threadIdx.x;
    #pragma unroll
    for (int c = 0; c < 32; c += 4) {
        const float4 v = *reinterpret_cast<const float4*>(&W[d * D_ + Tc * 32 + c]);
        const float xs[4] = {v.x, v.y, v.z, v.w};
        #pragma unroll
        for (int i = 0; i < 4; ++i) {
            unsigned short h, l;
            split_bf16(xs[i], h, l);
            ldb[d * 33 + c + i] = (uint32_t)h | ((uint32_t)l << 16);
        }
    }
    __syncthreads();
    const int lane = threadIdx.x & 63;
    const int pg   = threadIdx.x >> 6;
    #pragma unroll
    for (int kq = 0; kq < 4; ++kq) {
        const int ks = pg * 4 + kq;
        unsigned short hh[8], ll[8];
        #pragma unroll
        for (int j = 0; j < 8; ++j) {
            const uint32_t u = ldb[(ks * 16 + (lane >> 5) * 8 + j) * 33 + (lane & 31)];
            hh[j] = (unsigned short)(u & 0xffff);
            ll[j] = (unsigned short)(u >> 16);
        }
        const size_t o = ((size_t)((mat * 8 + Tc) * 16 + ks)) * 64 + lane;
        wph[o] = pack8(hh);
        wpl[o] = pack8(ll);
    }
}

// ---------------- P1: hr = relu(LN(|p-v| @ Wp1 + bp1)) ----------------
__global__ void prep_hr(const float* __restrict__ p_xyz, const float* __restrict__ v_xyz,
                        const float* __restrict__ Wp1, const float* __restrict__ bp1,
                        const float* __restrict__ ln_w, const float* __restrict__ ln_b,
                        float4* __restrict__ hr4) {
    const int r = blockIdx.x * 256 + threadIdx.x;
    if (r >= B_ * N_) return;
    const int b = r / N_;
    const float d0 = fabsf(p_xyz[r*3+0] - v_xyz[b*3+0]);
    const float d1 = fabsf(p_xyz[r*3+1] - v_xyz[b*3+1]);
    const float d2 = fabsf(p_xyz[r*3+2] - v_xyz[b*3+2]);
    float h[3];
    #pragma unroll
    for (int j = 0; j < 3; ++j)
        h[j] = d0*Wp1[0*3+j] + d1*Wp1[1*3+j] + d2*Wp1[2*3+j] + bp1[j];
    const float mu = (h[0]+h[1]+h[2]) * (1.0f/3.0f);
    const float e0 = h[0]-mu, e1 = h[1]-mu, e2 = h[2]-mu;
    const float var = (e0*e0 + e1*e1 + e2*e2) * (1.0f/3.0f);
    const float inv = rsqrtf(var + LN_EPS_);
    hr4[r] = make_float4(fmaxf(e0*inv*ln_w[0] + ln_b[0], 0.0f),
                         fmaxf(e1*inv*ln_w[1] + ln_b[1], 0.0f),
                         fmaxf(e2*inv*ln_w[2] + ln_b[2], 0.0f), 0.0f);
}

// ---------------- K1: projection GEMM -> packet-layout hi/lo outputs ----------------
// MODE 0=Q, 1=K(+pv), 2=V (V packets for PV consumption)
template<int MODE>
__global__ void gemm_qkv(const float* __restrict__ in,
                         const uint4* __restrict__ wph, const uint4* __restrict__ wpl,
                         const float* __restrict__ bias,
                         const float4* __restrict__ hr4,
                         const float* __restrict__ Wp2, const float* __restrict__ bp2,
                         uint4* __restrict__ oh, uint4* __restrict__ ol) {
    __shared__ uint32_t tb[4][32 * 33];
    const int tid  = threadIdx.x;
    const int lane = tid & 63;
    const int w    = tid >> 6;
    const int wr   = w & 1;
    const int wc   = w >> 1;
    const int lane31 = lane & 31;
    const int Trow = blockIdx.x * 2 + wr;                 // 32-row tile index (flat)
    const int rowA = Trow * 32 + lane31;
    const float* ap = in + (size_t)rowA * D_ + (lane >> 5) * 8;

    f32x16 acc[4];
    #pragma unroll
    for (int t = 0; t < 4; ++t) acc[t] = (f32x16)0.0f;

    union U8 { unsigned short u[8]; bf16x8 v; };
    #pragma unroll 4
    for (int ks = 0; ks < 16; ++ks) {
        const float4 f0 = *reinterpret_cast<const float4*>(ap + ks*16);
        const float4 f1 = *reinterpret_cast<const float4*>(ap + ks*16 + 4);
        const float xs[8] = {f0.x, f0.y, f0.z, f0.w, f1.x, f1.y, f1.z, f1.w};
        U8 ah, al;
        #pragma unroll
        for (int j = 0; j < 8; ++j) split_bf16(xs[j], ah.u[j], al.u[j]);
        #pragma unroll
        for (int t = 0; t < 4; ++t) {
            const size_t wb = ((size_t)((wc * 4 + t) * 16 + ks)) * 64 + lane;
            const bf16x8 bh = as_frag(wph[wb]);
            const bf16x8 bl = as_frag(wpl[wb]);
            MFMA32(acc[t], ah.v, bh);
            MFMA32(acc[t], ah.v, bl);
            MFMA32(acc[t], al.v, bh);
        }
    }

    float biasc[4], w0c[4], w1c[4], w2c[4], b2c[4];
    #pragma unroll
    for (int t = 0; t < 4; ++t) {
        const int cc = wc * 128 + t * 32 + lane31;
        biasc[t] = bias[cc];
        if (MODE == 1) {
            w0c[t] = Wp2[0*D_ + cc]; w1c[t] = Wp2[1*D_ + cc];
            w2c[t] = Wp2[2*D_ + cc]; b2c[t] = bp2[cc];
        }
    }
    float4 hv[16];
    if (MODE == 1) {
        #pragma unroll
        for (int r = 0; r < 16; ++r) hv[r] = hr4[Trow * 32 + cd_row(r, lane)];
    }

    #pragma unroll
    for (int t = 0; t < 4; ++t) {
        #pragma unroll
        for (int r = 0; r < 16; ++r) {
            float v = acc[t][r] + biasc[t];
            if (MODE == 1) v += hv[r].x*w0c[t] + hv[r].y*w1c[t] + hv[r].z*w2c[t] + b2c[t];
            unsigned short h, l;
            split_bf16(v, h, l);
            tb[w][cd_row(r, lane) * 33 + lane31] = (uint32_t)h | ((uint32_t)l << 16);
        }
        if (MODE != 2) {
            #pragma unroll
            for (int p = 0; p < 2; ++p) {
                const int ks = wc * 8 + t * 2 + p;
                unsigned short hh[8], ll[8];
                #pragma unroll
                for (int j = 0; j < 8; ++j) {
                    const uint32_t u = tb[w][lane31 * 33 + p * 16 + (lane >> 5) * 8 + j];
                    hh[j] = (unsigned short)(u & 0xffff);
                    ll[j] = (unsigned short)(u >> 16);
                }
                const size_t o = ((size_t)(Trow * 16 + ks)) * 64 + lane;
                oh[o] = pack8(hh);
                ol[o] = pack8(ll);
            }
        } else {
            #pragma unroll
            for (int h16 = 0; h16 < 2; ++h16) {
                const int gg = Trow * 2 + h16;            // flat_n/16
                const int dt = wc * 4 + t;
                unsigned short hh[8], ll[8];
                #pragma unroll
                for (int j = 0; j < 8; ++j) {
                    const uint32_t u = tb[w][(h16 * 16 + (lane >> 5) * 8 + j) * 33 + lane31];
                    hh[j] = (unsigned short)(u & 0xffff);
                    ll[j] = (unsigned short)(u >> 16);
                }
                const size_t o = ((size_t)(gg * 8 + dt)) * 64 + lane;
                oh[o] = pack8(hh);
                ol[o] = pack8(ll);
            }
        }
    }
}

// ---------------- K2: per-(b,n) softmax stats over m ----------------
// 256 blocks; block = 128 n (4 waves x 32-n K-stationary). Streams q-hi only
// (2-term hi/lo product; dropped l(q)*h(k) term contributes ~1e-3 to logits).
// bid%8 pins batch per XCD so the 1MB q stream stays L2-resident.
__device__ inline void load_q16(uint4 dst[16], const uint4* __restrict__ qh, size_t base) {
    #pragma unroll
    for (int ks = 0; ks < 16; ++ks) dst[ks] = qh[base + (size_t)ks * 64];
}
__device__ inline void mfma_tile2(f32x16& s0, f32x16& s1, const uint4 qb[16],
                                  const uint4 kfh[16], const uint4 kfl[16]) {
    #pragma unroll
    for (int ks = 0; ks < 16; ks += 2) {
        MFMA32(s0, as_frag(qb[ks]),   as_frag(kfh[ks]));
        MFMA32(s1, as_frag(qb[ks+1]), as_frag(kfh[ks+1]));
        MFMA32(s0, as_frag(qb[ks]),   as_frag(kfl[ks]));
        MFMA32(s1, as_frag(qb[ks+1]), as_frag(kfl[ks+1]));
    }
}
__device__ inline void upd_stats(const f32x16& s0, const f32x16& s1, float& cm, float& cs) {
    float sm[16], tmax = -INFINITY;
    #pragma unroll
    for (int r = 0; r < 16; ++r) { sm[r] = (s0[r] + s1[r]) * SCALE_; tmax = fmaxf(tmax, sm[r]); }
    const float nm = fmaxf(cm, tmax);
    const float f  = __expf(cm - nm);
    float ts = 0.0f;
    #pragma unroll
    for (int r = 0; r < 16; ++r) ts += __expf(sm[r] - nm);
    cs = cs * f + ts;
    cm = nm;
}

__global__ __launch_bounds__(256, 1)
void col_stats(const uint4* __restrict__ qh,
               const uint4* __restrict__ kh, const uint4* __restrict__ kl,
               float* __restrict__ cmax, float* __restrict__ cinv) {
    const int tid  = threadIdx.x;
    const int lane = tid & 63;
    const int w    = tid >> 6;
    const int bid  = blockIdx.x;
    const int x8   = bid & 7;
    const int b    = x8 >> 2;                       // XCD batch pinning
    const int loc  = (bid >> 3) * 4 + (x8 & 3);     // 0..127
    const int n0   = loc * 128 + w * 32;            // within-batch n base (this wave)
    const int Tk   = (b * N_ + n0) >> 5;

    uint4 kfh[16], kfl[16];
    #pragma unroll
    for (int ks = 0; ks < 16; ++ks) {
        kfh[ks] = kh[((size_t)(Tk * 16 + ks)) * 64 + lane];
        kfl[ks] = kl[((size_t)(Tk * 16 + ks)) * 64 + lane];
    }

    const size_t qbase = ((size_t)(b * (M_ / 32)) * 16) * 64 + lane;
    uint4 qA[16], qB[16];
    load_q16(qA, qh, qbase);

    float cm = -INFINITY, cs = 0.0f;
    const f32x16 z = (f32x16)0.0f;
    for (int m2 = 0; m2 < 32; ++m2) {
        const int t1 = 2 * m2 + 1;
        load_q16(qB, qh, qbase + (size_t)t1 * 16 * 64);
        f32x16 sa0 = z, sa1 = z;
        mfma_tile2(sa0, sa1, qA, kfh, kfl);
        upd_stats(sa0, sa1, cm, cs);
        if (m2 < 31) load_q16(qA, qh, qbase + (size_t)(t1 + 1) * 16 * 64);
        f32x16 sb0 = z, sb1 = z;
        mfma_tile2(sb0, sb1, qB, kfh, kfl);
        upd_stats(sb0, sb1, cm, cs);
    }
    const float ocm = __shfl_xor(cm, 32, 64);
    const float ocs = __shfl_xor(cs, 32, 64);
    const float nm  = fmaxf(cm, ocm);
    const float tot = cs * __expf(cm - nm) + ocs * __expf(ocm - nm);
    if (lane < 32) {
        cmax[b * N_ + n0 + lane] = nm;
        cinv[b * N_ + n0 + lane] = 1.0f / tot;
    }
}

// ---------------- K3: out = v_features ----------------
__global__ void init_out(const float* __restrict__ src, float* __restrict__ dst) {
    const int i = blockIdx.x * blockDim.x + threadIdx.x;
    reinterpret_cast<float4*>(dst)[i] = reinterpret_cast<const float4*>(src)[i];
}

// ---------------- K4: out += softmax-weighted V ----------------
__global__ void attn_out(const uint4* __restrict__ qh, const uint4* __restrict__ ql,
                         const uint4* __restrict__ kh, const uint4* __restrict__ kl,
                         const uint4* __restrict__ vh, const uint4* __restrict__ vl,
                         const float* __restrict__ cmax, const float* __restrict__ cinv,
                         float* __restrict__ out) {
    __shared__ unsigned short Ph[64 * 72];
    __shared__ unsigned short Pl[64 * 72];
    const int tid  = threadIdx.x;
    const int lane = tid & 63;
    const int w    = tid >> 6;
    const int wm   = w & 1;
    const int wh   = w >> 1;
    const int lane31 = lane & 31;
    const int kh8    = (lane >> 5) * 8;

    // bid = low3 + 8*(mt*4 + ghi): all 32 m-tiles of group g share XCD (bid%8)
    const int bid  = blockIdx.x;
    const int low3 = bid & 7;
    const int rest = bid >> 3;
    const int ghi  = rest & 3;
    const int mt   = rest >> 2;
    const int g    = ghi * 8 + low3;
    const int b    = g >> 4;
    const int ns   = g & 15;
    const int m0   = mt * 64;

    const size_t qb = ((size_t)(((b * M_ + m0) >> 5) + wm) * 16) * 64 + lane;

    f32x16 oacc[4];
    #pragma unroll
    for (int t = 0; t < 4; ++t) oacc[t] = (f32x16)0.0f;

    for (int c = 0; c < NPB_ / 64; ++c) {
        const int nbase = ns * NPB_ + c * 64;
        // ---- phase A: S quadrant (wm rows, wh n-cols) ----
        const size_t kb = ((size_t)(((b * N_ + nbase) >> 5) + wh) * 16) * 64 + lane;
        f32x16 s = (f32x16)0.0f;
        #pragma unroll 8
        for (int ks = 0; ks < 16; ++ks) {
            const bf16x8 ah = as_frag(qh[qb + ks * 64]);
            const bf16x8 al = as_frag(ql[qb + ks * 64]);
            const bf16x8 bh = as_frag(kh[kb + ks * 64]);
            const bf16x8 bl = as_frag(kl[kb + ks * 64]);
            MFMA32(s, ah, bh);
            MFMA32(s, ah, bl);
            MFMA32(s, al, bh);
        }
        const int ncol = nbase + wh * 32 + lane31;
        const float cmv = cmax[b * N_ + ncol];
        const float civ = cinv[b * N_ + ncol];
        #pragma unroll
        for (int r = 0; r < 16; ++r) {
            const float p = __expf(s[r] * SCALE_ - cmv) * civ;
            unsigned short hph, hpl;
            split_bf16(p, hph, hpl);
            const int row = wm * 32 + cd_row(r, lane);
            const int col = wh * 32 + lane31;
            Ph[row * 72 + col] = hph;
            Pl[row * 72 + col] = hpl;
        }
        __syncthreads();
        // ---- phase B: oacc += P @ V ----
        const unsigned short* prh = Ph + (wm * 32 + lane31) * 72 + kh8;
        const unsigned short* prl = Pl + (wm * 32 + lane31) * 72 + kh8;
        const size_t vb0 = ((size_t)((b * N_ + nbase) >> 4)) * 8 * 64;
        #pragma unroll
        for (int k2 = 0; k2 < 4; ++k2) {
            const bf16x8 a2h = as_frag(*reinterpret_cast<const uint4*>(prh + k2 * 16));
            const bf16x8 a2l = as_frag(*reinterpret_cast<const uint4*>(prl + k2 * 16));
            #pragma unroll
            for (int t = 0; t < 4; ++t) {
                const size_t vo = vb0 + ((size_t)(k2 * 8 + wh * 4 + t)) * 64 + lane;
                const bf16x8 b2h = as_frag(vh[vo]);
                const bf16x8 b2l = as_frag(vl[vo]);
                MFMA32(oacc[t], a2h, b2h);
                MFMA32(oacc[t], a2h, b2l);
                MFMA32(oacc[t], a2l, b2h);
            }
        }
        __syncthreads();
    }
    #pragma unroll
    for (int t = 0; t < 4; ++t) {
        #pragma unroll
        for (int r = 0; r < 16; ++r) {
            const int row  = m0 + wm * 32 + cd_row(r, lane);
            const int dcol = wh * 128 + t * 32 + lane31;
            atomicAdd(&out[((size_t)(b * M_ + row)) * D_ + dcol], oacc[t][r]);
        }
    }
}

} // anonymous namespace

extern "C" void kernel_launch(void* const* d_in, const int* in_sizes, int n_in,
                              void* d_out, int out_size, void* d_ws, size_t ws_size,
                              hipStream_t stream) {
    const float* p_xyz      = (const float*)d_in[0];
    const float* v_xyz      = (const float*)d_in[1];
    const float* p_features = (const float*)d_in[2];
    const float* v_features = (const float*)d_in[3];
    const float* Wq  = (const float*)d_in[4];
    const float* bq  = (const float*)d_in[5];
    const float* Wk  = (const float*)d_in[6];
    const float* bk  = (const float*)d_in[7];
    const float* Wv  = (const float*)d_in[8];
    const float* bv  = (const float*)d_in[9];
    const float* Wp1 = (const float*)d_in[10];
    const float* bp1 = (const float*)d_in[11];
    const float* lnw = (const float*)d_in[12];
    const float* lnb = (const float*)d_in[13];
    const float* Wp2 = (const float*)d_in[14];
    const float* bp2 = (const float*)d_in[15];
    float* out = (float*)d_out;

    // ---- workspace carve-up (256B aligned), ~70.5 MB ----
    char* p = (char*)d_ws;
    auto alloc = [&](size_t bytes) {
        void* r = (void*)p;
        p += (bytes + 255) & ~(size_t)255;
        return r;
    };
    uint4* qh  = (uint4*)alloc((size_t)B_*M_*D_*2);   // bf16 hi plane, packet order
    uint4* ql  = (uint4*)alloc((size_t)B_*M_*D_*2);
    uint4* kh  = (uint4*)alloc((size_t)B_*N_*D_*2);
    uint4* kl  = (uint4*)alloc((size_t)B_*N_*D_*2);
    uint4* vh  = (uint4*)alloc((size_t)B_*N_*D_*2);
    uint4* vl  = (uint4*)alloc((size_t)B_*N_*D_*2);
    uint4* wph = (uint4*)alloc((size_t)3*D_*D_*2);
    uint4* wpl = (uint4*)alloc((size_t)3*D_*D_*2);
    float4* hr4 = (float4*)alloc((size_t)B_*N_*16);
    float*  cm  = (float*)alloc((size_t)B_*N_*4);
    float*  ci  = (float*)alloc((size_t)B_*N_*4);

    constexpr size_t WMAT = (size_t)D_*D_/8;   // uint4 per weight matrix

    prep_wt<<<3*8, 256, 0, stream>>>(Wq, Wk, Wv, wph, wpl);
    prep_hr<<<(B_*N_)/256, 256, 0, stream>>>(p_xyz, v_xyz, Wp1, bp1, lnw, lnb, hr4);

    gemm_qkv<0><<<(B_*M_)/64, 256, 0, stream>>>(v_features, wph + 0*WMAT, wpl + 0*WMAT,
                                                bq, hr4, Wp2, bp2, qh, ql);
    gemm_qkv<1><<<(B_*N_)/64, 256, 0, stream>>>(p_features, wph + 1*WMAT, wpl + 1*WMAT,
                                                bk, hr4, Wp2, bp2, kh, kl);
    gemm_qkv<2><<<(B_*N_)/64, 256, 0, stream>>>(p_features, wph + 2*WMAT, wpl + 2*WMAT,
                                                bv, hr4, Wp2, bp2, vh, vl);

    col_stats<<<256, 256, 0, stream>>>(qh, kh, kl, cm, ci);
    init_out<<<(B_*M_*D_/4)/256, 256, 0, stream>>>(v_features, out);
    attn_out<<<B_*NS_*(M_/64), 256, 0, stream>>>(qh, ql, kh, kl, vh, vl, cm, ci, out);
}